// Round 1
// baseline (76.717 us; speedup 1.0000x reference)
//
#include <hip/hip_runtime.h>

// TripletLoss with per-class margins.
// d_ap = ||a - p + 1e-6||_2, d_an = ||a - n + 1e-6||_2 (eps added to the
// per-element difference, matching torch pairwise_distance / the jax ref).
// loss = mean(relu(d_ap - d_an + margin[cs]))
//
// Layout: 32-lane group per row (D=128 fp32 -> 32 x float4, fully coalesced).
// Grid-stride over rows; deterministic two-pass reduction via d_ws.

#define TL_D 128
#define TL_BLOCK 256
#define TL_MAXBLOCKS 2048

__global__ __launch_bounds__(TL_BLOCK) void triplet_partial_kernel(
    const float* __restrict__ a,
    const float* __restrict__ p,
    const float* __restrict__ n,
    const long long* __restrict__ cs,
    float* __restrict__ partials,
    int nrows)
{
    const int tid = threadIdx.x;
    const int lane32 = tid & 31;                     // lane within 32-lane row-group
    const int groupInBlock = tid >> 5;               // 8 groups per 256-thread block
    const int groupsPerBlock = TL_BLOCK >> 5;
    const int gGroup = blockIdx.x * groupsPerBlock + groupInBlock;
    const int totalGroups = gridDim.x * groupsPerBlock;

    float local = 0.0f;

    for (int row = gGroup; row < nrows; row += totalGroups) {
        const int base = row * TL_D + lane32 * 4;
        const float4 a4 = *reinterpret_cast<const float4*>(a + base);
        const float4 p4 = *reinterpret_cast<const float4*>(p + base);
        const float4 n4 = *reinterpret_cast<const float4*>(n + base);

        float dap = 0.0f, dan = 0.0f;
        {
            float d;
            d = a4.x - p4.x + 1e-6f; dap += d * d;
            d = a4.y - p4.y + 1e-6f; dap += d * d;
            d = a4.z - p4.z + 1e-6f; dap += d * d;
            d = a4.w - p4.w + 1e-6f; dap += d * d;
            d = a4.x - n4.x + 1e-6f; dan += d * d;
            d = a4.y - n4.y + 1e-6f; dan += d * d;
            d = a4.z - n4.z + 1e-6f; dan += d * d;
            d = a4.w - n4.w + 1e-6f; dan += d * d;
        }

        // Butterfly reduce across the 32 lanes of this group.
        // Masks 1..16 keep lanes within their 32-lane half of the 64-wave.
        #pragma unroll
        for (int m = 1; m <= 16; m <<= 1) {
            dap += __shfl_xor(dap, m, 64);
            dan += __shfl_xor(dan, m, 64);
        }

        if (lane32 == 0) {
            const int c = (int)cs[row];
            // select chain (no runtime-indexed array -> no scratch)
            const float margin = (c == 0) ? 0.10f
                               : (c == 1) ? 0.085f
                               : (c == 2) ? 0.07f
                               : 0.04f;
            const float loss = sqrtf(dap) - sqrtf(dan) + margin;
            local += fmaxf(loss, 0.0f);
        }
    }

    // Block-level reduction of per-thread locals.
    __shared__ float sdata[TL_BLOCK];
    sdata[tid] = local;
    __syncthreads();
    #pragma unroll
    for (int s = TL_BLOCK / 2; s > 0; s >>= 1) {
        if (tid < s) sdata[tid] += sdata[tid + s];
        __syncthreads();
    }
    if (tid == 0) partials[blockIdx.x] = sdata[0];
}

__global__ __launch_bounds__(TL_BLOCK) void triplet_final_kernel(
    const float* __restrict__ partials,
    int nparts,
    float* __restrict__ out,
    float invB)
{
    __shared__ float sdata[TL_BLOCK];
    float local = 0.0f;
    for (int i = threadIdx.x; i < nparts; i += TL_BLOCK) local += partials[i];
    sdata[threadIdx.x] = local;
    __syncthreads();
    #pragma unroll
    for (int s = TL_BLOCK / 2; s > 0; s >>= 1) {
        if (threadIdx.x < s) sdata[threadIdx.x] += sdata[threadIdx.x + s];
        __syncthreads();
    }
    if (threadIdx.x == 0) out[0] = sdata[0] * invB;
}

extern "C" void kernel_launch(void* const* d_in, const int* in_sizes, int n_in,
                              void* d_out, int out_size, void* d_ws, size_t ws_size,
                              hipStream_t stream)
{
    const float*     a   = (const float*)d_in[0];
    const float*     p   = (const float*)d_in[1];
    const float*     n   = (const float*)d_in[2];
    const long long* cs  = (const long long*)d_in[3];
    float*           out = (float*)d_out;
    float*           partials = (float*)d_ws;

    const int nrows = in_sizes[3];  // B = 262144 (cs element count)

    int nblocks = TL_MAXBLOCKS;
    const int maxParts = (int)(ws_size / sizeof(float));
    if (nblocks > maxParts) nblocks = maxParts;
    if (nblocks < 1) nblocks = 1;

    triplet_partial_kernel<<<nblocks, TL_BLOCK, 0, stream>>>(a, p, n, cs, partials, nrows);
    triplet_final_kernel<<<1, TL_BLOCK, 0, stream>>>(partials, nblocks, out, 1.0f / (float)nrows);
}